// Round 14
// baseline (306.139 us; speedup 1.0000x reference)
//
#include <hip/hip_runtime.h>

// MultiHeadModel routed MoE (E=8), round 14.
// = round 11 (best passing structure) with GEMM narrowed to BN=64:
//  - 2x the GEMM blocks (l1: 1280 = 5/CU, l2: 2560 = 10/CU) at UNCHANGED
//    logical B traffic -- the occupancy lever, applied cleanly this time
//    (NO launch_bounds forcing; r9's spill disaster came from forcing).
//  - LDS 32 KiB (A 3x8KB + B 2x4KB) -> 5 blocks/CU fit; acc[4][2], VGPR ~75.
//  - Schedule, swizzles, waits = r11 verbatim (compiler-managed writeB wait).
//   routing -> k_prep{cvtW1i ∥ cvtW1g ∥ a_build}
//           -> k_main1{gemm_l1 both heads ∥ cvtW2g ∥ copy_vt}
//           -> k_main2{gemm_l2 ∥ immune}

#define B_N 4096
#define DV  1024
#define DD  2048
#define HH  1024
#define GG  4096
#define EE  8
#define BM  128
#define MAXRB 40
#define PERM_N (MAXRB * BM)

typedef __bf16 bf16x8 __attribute__((ext_vector_type(8)));
typedef float f32x4 __attribute__((ext_vector_type(4)));
typedef unsigned short u16x8v __attribute__((ext_vector_type(8)));

#define H_CNT 0
#define H_FIL 8
#define H_OFF 16
#define H_NRB 24
#define H_BLK 32

static __device__ __forceinline__ unsigned short f2bf(float f) {
  return __builtin_bit_cast(unsigned short, (__bf16)f);
}
static __device__ __forceinline__ float bf2f(unsigned short s) {
  return __builtin_bit_cast(float, (unsigned)s << 16);
}
static __device__ __forceinline__ void gload16(const void* g, void* l) {
  __builtin_amdgcn_global_load_lds(
      (const __attribute__((address_space(1))) unsigned int*)g,
      (__attribute__((address_space(3))) unsigned int*)l, 16, 0, 0);
}

// ---------------- routing: one block, 1024 threads ---------------------------
__global__ __launch_bounds__(1024) void routing(const int* __restrict__ organ,
                                                int* __restrict__ hdr,
                                                int* __restrict__ perm) {
  __shared__ int cnt[EE], fil[EE], off[EE];
  const int tid = threadIdx.x;
  if (tid < EE) { cnt[tid] = 0; fil[tid] = 0; }
  __syncthreads();
#pragma unroll
  for (int i = 0; i < 4; ++i) atomicAdd(&cnt[organ[tid + (i << 10)]], 1);
#pragma unroll
  for (int i = 0; i < 5; ++i) perm[tid + (i << 10)] = -1;
  __syncthreads();
  if (tid == 0) {
    int acc = 0;
    for (int e = 0; e < EE; ++e) {
      off[e] = acc;
      hdr[H_OFF + e] = acc;
      hdr[H_CNT + e] = cnt[e];
      int nb = (cnt[e] + BM - 1) >> 7;
      int rb0 = acc >> 7;
      for (int i = 0; i < nb; ++i) hdr[H_BLK + rb0 + i] = e;
      acc += nb << 7;
    }
    hdr[H_NRB] = acc >> 7;
  }
  __syncthreads();
#pragma unroll
  for (int i = 0; i < 4; ++i) {
    int b = tid + (i << 10);
    int e = organ[b];
    int slot = off[e] + atomicAdd(&fil[e], 1);
    perm[slot] = b;
  }
}

// ---------------- weight convert+transpose: fp32 [e][K][N] -> bf16 [e][N][K] -
static __device__ __forceinline__ void wcvt_body(
    const float* __restrict__ in, unsigned short* __restrict__ out,
    int K, int N, int bx, unsigned short* ls) {  // ls: 64*72 shorts
  const int nn = N >> 6, nk = K >> 6;
  const int e = bx / (nk * nn);
  int rem = bx - e * nk * nn;
  const int K0 = (rem / nn) << 6, N0 = (rem % nn) << 6;
  const size_t ein = (size_t)e * K * N;
  const int tid = threadIdx.x;
  const int kr = tid >> 4, n0 = (tid & 15) << 2;
#pragma unroll
  for (int p = 0; p < 4; ++p) {
    int k = (p << 4) + kr;
    float4 f = *(const float4*)&in[ein + (size_t)(K0 + k) * N + N0 + n0];
    ls[(n0 + 0) * 72 + k] = f2bf(f.x);
    ls[(n0 + 1) * 72 + k] = f2bf(f.y);
    ls[(n0 + 2) * 72 + k] = f2bf(f.z);
    ls[(n0 + 3) * 72 + k] = f2bf(f.w);
  }
  __syncthreads();
  const int n = tid >> 2, kc = (tid & 3) << 4;
  u16x8v a = *(const u16x8v*)&ls[n * 72 + kc];
  u16x8v b = *(const u16x8v*)&ls[n * 72 + kc + 8];
  size_t o = (size_t)e * N * K + (size_t)(N0 + n) * K + K0 + kc;
  *(u16x8v*)&out[o] = a;
  *(u16x8v*)&out[o + 8] = b;
}

// ---------------- a_build: 4 rows per block ----------------------------------
static __device__ __forceinline__ void abuild_body(
    int bx, const float* __restrict__ vis, const float* __restrict__ txt,
    const int* __restrict__ hdr, const int* __restrict__ perm,
    unsigned short* __restrict__ Abuf) {
  const int nr = hdr[H_NRB] << 7;
  const int tid = threadIdx.x;
  const int c = tid << 3;
  const float* srcbase = (c < DV) ? vis : txt;
  const int cc = (c < DV) ? c : c - DV;
#pragma unroll
  for (int p = 0; p < 4; ++p) {
    int r = (bx << 2) + p;
    if (r >= nr) return;
    int smp = perm[r];
    u16x8v v;
    if (smp >= 0) {
      const float* src = srcbase + (size_t)smp * 1024 + cc;
      float4 a = *(const float4*)src, b = *(const float4*)(src + 4);
      v[0] = f2bf(a.x); v[1] = f2bf(a.y); v[2] = f2bf(a.z); v[3] = f2bf(a.w);
      v[4] = f2bf(b.x); v[5] = f2bf(b.y); v[6] = f2bf(b.z); v[7] = f2bf(b.w);
    } else {
#pragma unroll
      for (int i = 0; i < 8; ++i) v[i] = 0;
    }
    *(u16x8v*)&Abuf[(size_t)r * DD + c] = v;
  }
}

static __device__ __forceinline__ void copy_body(
    int bx, const float4* __restrict__ v, const float4* __restrict__ t,
    float4* __restrict__ ov, float4* __restrict__ ot) {
  const int n4 = B_N * DV / 4;
  for (int i = bx * 256 + (int)threadIdx.x; i < n4; i += 1024 * 256) {
    ov[i] = v[i];
    ot[i] = t[i];
  }
}

// ---------------- GEMM core BN=64: A gload_lds 3-buf, B bf16 reg-staged ------
// LDS shorts: A bufs 3 x 4096 @0; B bufs 2 x 2048 @12288 (32 KiB total).
// A rows [128][32], chunk swizzle c ^= (row>>1)&3 (pre-swizzled gload source).
// B rows [64][32], same chunk swizzle on the ds_write side.
// Schedule = r11 verbatim (compiler-managed waits; writeB's implicit vmcnt
// wait on bv(t+1) -- issued after issueA(t+1) -- retires A(t+1)).
template <int KDIM>
static __device__ __forceinline__ void gemm_bb64(
    const unsigned short* __restrict__ Aseg,  // [128][KDIM] bf16 row-major
    const unsigned short* __restrict__ Bseg,  // [64][KDIM] bf16 n-major
    unsigned short* smem, f32x4 (&acc)[4][2]) {
  const int tid = threadIdx.x;
  const int lane = tid & 63;
  const int wr = ((tid >> 6) >> 1) << 6, wc = ((tid >> 6) & 1) << 5;
  const int lr = lane & 15;
  const int arow = tid >> 2;
  const int kq = (((tid & 3) ^ ((arow >> 1) & 3)) << 3);
  const int wbase = (tid & 192) << 3;
  const int bn = tid & 63;               // B row (n)
  const int bc = tid >> 6;               // chunk 0..3
  const int bs = (bn >> 1) & 3;
  const int bslot = ((bc ^ bs) << 3);
  constexpr int NT = KDIM / 32;

  u16x8v bvE, bvO;

  auto issueA = [&](int ab, int k0) {
    unsigned short* d = smem + ab * 4096 + wbase;
    gload16(Aseg + (size_t)arow * KDIM + k0 + kq, d);
    gload16(Aseg + (size_t)(64 + arow) * KDIM + k0 + kq, d + 2048);
  };
  auto issueB = [&](u16x8v& bv, int k0) {
    bv = *(const u16x8v*)(Bseg + (size_t)bn * KDIM + k0 + (bc << 3));
  };
  auto writeB = [&](int bb, u16x8v& bv) {
    *(u16x8v*)(smem + 12288 + bb * 2048 + (bn << 5) + bslot) = bv;
  };
  auto compute = [&](int ab, int bb) {
    bf16x8 af[4], bfr[2];
#pragma unroll
    for (int m = 0; m < 4; ++m) {
      const int r = wr + m * 16 + lr;
      const int cs = ((lane >> 4) ^ ((r >> 1) & 3)) << 3;
      af[m] = *(const bf16x8*)&smem[ab * 4096 + r * 32 + cs];
    }
#pragma unroll
    for (int n = 0; n < 2; ++n) {
      const int fr = wc + n * 16 + lr;
      const int cs = ((lane >> 4) ^ ((fr >> 1) & 3)) << 3;
      bfr[n] = *(const bf16x8*)&smem[12288 + bb * 2048 + fr * 32 + cs];
    }
#pragma unroll
    for (int m = 0; m < 4; ++m)
#pragma unroll
      for (int n = 0; n < 2; ++n)
        acc[m][n] = __builtin_amdgcn_mfma_f32_16x16x32_bf16(af[m], bfr[n], acc[m][n], 0, 0, 0);
  };

  issueA(0, 0);
  __builtin_amdgcn_sched_barrier(0);
  issueB(bvE, 0);
  writeB(0, bvE);
  issueA(1, 32);
  __builtin_amdgcn_sched_barrier(0);
  issueB(bvO, 32);
  asm volatile("s_waitcnt lgkmcnt(0)" ::: "memory");
  __builtin_amdgcn_s_barrier();
  __builtin_amdgcn_sched_barrier(0);

  auto phase = [&](int t, int abI, int abC, u16x8v& bvIss, u16x8v& bvWr,
                   int bbW, int bbC) {
    if (t + 2 < NT) issueA(abI, (t + 2) << 5);
    __builtin_amdgcn_sched_barrier(0);
    if (t + 2 < NT) issueB(bvIss, (t + 2) << 5);
    __builtin_amdgcn_sched_barrier(0);
    compute(abC, bbC);
    if (t + 1 < NT) writeB(bbW, bvWr);
    asm volatile("s_waitcnt lgkmcnt(0)" ::: "memory");
    __builtin_amdgcn_s_barrier();
    __builtin_amdgcn_sched_barrier(0);
  };

  int abI = 2, abC = 0;
  for (int t = 0; t < NT; t += 2) {
    phase(t, abI, abC, bvE, bvO, 1, 0);
    abI = (abI == 2) ? 0 : abI + 1;
    abC = (abC == 2) ? 0 : abC + 1;
    phase(t + 1, abI, abC, bvO, bvE, 0, 1);
    abI = (abI == 2) ? 0 : abI + 1;
    abC = (abC == 2) ? 0 : abC + 1;
  }
}

// ---------------- k_prep: cvt(W1i) ∥ cvt(W1g) ∥ a_build ----------------------
#define G_CVT1 (EE * (DD >> 6) * (HH >> 6))   // 4096
#define G_AB   (PERM_N / 4)                   // 1280
__global__ __launch_bounds__(256) void k_prep(
    const float* __restrict__ W1i, const float* __restrict__ W1g,
    unsigned short* __restrict__ W1i_t, unsigned short* __restrict__ W1g_t,
    const float* __restrict__ vis, const float* __restrict__ txt,
    const int* __restrict__ hdr, const int* __restrict__ perm,
    unsigned short* __restrict__ Abuf) {
  __shared__ __align__(16) unsigned short sm[64 * 72];
  int bx = blockIdx.x;
  if (bx < G_CVT1) { wcvt_body(W1i, W1i_t, DD, HH, bx, sm); return; }
  bx -= G_CVT1;
  if (bx < G_CVT1) { wcvt_body(W1g, W1g_t, DD, HH, bx, sm); return; }
  bx -= G_CVT1;
  abuild_body(bx, vis, txt, hdr, perm, Abuf);
}

// ---------------- k_main1: gemm_l1 BN=64 (both heads) ∥ cvtW2g ∥ copy_vt -----
#define G_G1   (MAXRB * 32)                   // 1280 (16 col-blocks x 2 heads)
#define G_CVT2 (EE * (HH >> 6) * (GG >> 6))   // 8192
#define G_COPY 1024
__global__ __launch_bounds__(256) void k_main1(
    const unsigned short* __restrict__ Abuf,
    const unsigned short* __restrict__ W1i_t, const unsigned short* __restrict__ W1g_t,
    const float* __restrict__ b1i, const float* __restrict__ b1g,
    const int* __restrict__ hdr, unsigned short* __restrict__ H1,
    unsigned short* __restrict__ H2, const float* __restrict__ W2g,
    unsigned short* __restrict__ W2g_t, const float4* __restrict__ vis4,
    const float4* __restrict__ txt4, float4* __restrict__ ov,
    float4* __restrict__ ot) {
  __shared__ __align__(16) unsigned short smem[16384];  // 32 KiB
  int bx = blockIdx.x;
  if (bx >= G_G1) {
    bx -= G_G1;
    if (bx < G_CVT2) { wcvt_body(W2g, W2g_t, HH, GG, bx, smem); return; }
    copy_body(bx - G_CVT2, vis4, txt4, ov, ot);
    return;
  }
  const int id = (bx & 7) * (G_G1 >> 3) + (bx >> 3);  // XCD swizzle (1280%8==0)
  const int rb = id % MAXRB;
  if (rb >= hdr[H_NRB]) return;
  const int sub = id / MAXRB;            // 0..31
  const int head = sub >> 4, cb = (sub & 15) << 6;
  const int e = hdr[H_BLK + rb];
  const unsigned short* Wt = (head ? W1g_t : W1i_t) + (size_t)e * HH * DD + (size_t)cb * DD;
  const float* bias = (head ? b1g : b1i) + e * HH;
  unsigned short* Hout = head ? H2 : H1;
  const int tid = threadIdx.x;
  const int lane = tid & 63, wave = tid >> 6;
  const int wr = (wave >> 1) << 6, wc = (wave & 1) << 5;
  const int lr = lane & 15;

  f32x4 acc[4][2];
#pragma unroll
  for (int m = 0; m < 4; ++m)
#pragma unroll
    for (int n = 0; n < 2; ++n) acc[m][n] = (f32x4){0.f, 0.f, 0.f, 0.f};

  gemm_bb64<DD>(Abuf + (size_t)rb * BM * DD, Wt, smem, acc);
  __syncthreads();

  // epilogue: bias+relu -> bf16 swizzled LDS [128][64] -> coalesced stores
  const int r0l = wr + ((lane >> 4) << 2);
#pragma unroll
  for (int n = 0; n < 2; ++n) {
    const int col = wc + n * 16 + lr;
    const float bv = bias[cb + col];
#pragma unroll
    for (int m = 0; m < 4; ++m)
#pragma unroll
      for (int v = 0; v < 4; ++v) {
        int row = r0l + m * 16 + v;
        float x = acc[m][n][v] + bv;
        x = x > 0.f ? x : 0.f;
        smem[((row << 6) + col) ^ ((row & 7) << 3)] = f2bf(x);
      }
  }
  __syncthreads();
#pragma unroll
  for (int c = 0; c < 4; ++c) {
    int q = c * 256 + tid;
    int row = q >> 3, ch = q & 7;
    int off = ((row << 6) + (ch << 3)) ^ ((row & 7) << 3);
    u16x8v val = *(const u16x8v*)&smem[off];
    *(u16x8v*)&Hout[(size_t)(rb * BM + row) * HH + cb + (ch << 3)] = val;
  }
}

// ---------------- immune dot -------------------------------------------------
static __device__ __forceinline__ void immune_body(
    int bx, const int* __restrict__ hdr, const int* __restrict__ perm,
    const unsigned short* __restrict__ H1, const float* __restrict__ W2,
    const float* __restrict__ b2, float* __restrict__ out) {
  const int nrb = hdr[H_NRB];
  const int r = bx * 4 + (threadIdx.x >> 6);
  if (r >= nrb * BM) return;
  const int b = perm[r];
  if (b < 0) return;
  const int e = hdr[H_BLK + (r >> 7)];
  const int lane = threadIdx.x & 63;
  const unsigned short* h = H1 + (size_t)r * HH + lane * 16;
  const float* w = W2 + (size_t)e * HH + lane * 16;
  float s = 0.f;
#pragma unroll
  for (int i = 0; i < 16; ++i) s += bf2f(h[i]) * w[i];
#pragma unroll
  for (int off = 32; off >= 1; off >>= 1) s += __shfl_xor(s, off, 64);
  if (lane == 0) out[b] = s + b2[e];
}

// ---------------- k_main2: gemm_l2 BN=64 ∥ immune ----------------------------
#define G_G2 (MAXRB * 64)   // 2560
__global__ __launch_bounds__(256) void k_main2(
    const unsigned short* __restrict__ H2buf,
    const unsigned short* __restrict__ W2g_t, const float* __restrict__ b2g,
    const int* __restrict__ hdr, const int* __restrict__ perm,
    float* __restrict__ outg, const unsigned short* __restrict__ H1,
    const float* __restrict__ W2i, const float* __restrict__ b2i,
    float* __restrict__ outi) {
  __shared__ __align__(16) unsigned short smem[16384];  // 32 KiB
  int bx = blockIdx.x;
  if (bx >= G_G2) {
    immune_body(bx - G_G2, hdr, perm, H1, W2i, b2i, outi);
    return;
  }
  const int id = (bx & 7) * (G_G2 >> 3) + (bx >> 3);  // XCD swizzle (2560%8==0)
  const int rb = id % MAXRB;
  if (rb >= hdr[H_NRB]) return;
  const int cb = (id / MAXRB) << 6;      // 64 col-blocks of 64
  const int e = hdr[H_BLK + rb];
  const unsigned short* Wt = W2g_t + (size_t)e * GG * HH + (size_t)cb * HH;
  const int tid = threadIdx.x;
  const int lane = tid & 63, wave = tid >> 6;
  const int wr = (wave >> 1) << 6, wc = (wave & 1) << 5;
  const int lr = lane & 15;

  f32x4 acc[4][2];
#pragma unroll
  for (int m = 0; m < 4; ++m)
#pragma unroll
    for (int n = 0; n < 2; ++n) acc[m][n] = (f32x4){0.f, 0.f, 0.f, 0.f};

  gemm_bb64<HH>(H2buf + (size_t)rb * BM * HH, Wt, smem, acc);
  __syncthreads();

  // epilogue: bias -> bf16 swizzled LDS [128][64] -> fp32 scatter via perm
  const int r0l = wr + ((lane >> 4) << 2);
#pragma unroll
  for (int n = 0; n < 2; ++n) {
    const int col = wc + n * 16 + lr;
    const float bv = b2g[e * GG + cb + col];
#pragma unroll
    for (int m = 0; m < 4; ++m)
#pragma unroll
      for (int v = 0; v < 4; ++v) {
        int row = r0l + m * 16 + v;
        smem[((row << 6) + col) ^ ((row & 7) << 3)] = f2bf(acc[m][n][v] + bv);
      }
  }
  __syncthreads();
#pragma unroll
  for (int c = 0; c < 4; ++c) {
    int q = c * 256 + tid;
    int row = q >> 3, ch = q & 7;
    int sm = perm[rb * BM + row];
    if (sm < 0) continue;
    int off = ((row << 6) + (ch << 3)) ^ ((row & 7) << 3);
    u16x8v val = *(const u16x8v*)&smem[off];
    float4 f0, f1;
    f0.x = bf2f(val[0]); f0.y = bf2f(val[1]); f0.z = bf2f(val[2]); f0.w = bf2f(val[3]);
    f1.x = bf2f(val[4]); f1.y = bf2f(val[5]); f1.z = bf2f(val[6]); f1.w = bf2f(val[7]);
    float* dst = outg + (size_t)sm * GG + cb + (ch << 3);
    *(float4*)dst = f0;
    *(float4*)(dst + 4) = f1;
  }
}

// ================= host ======================================================
extern "C" void kernel_launch(void* const* d_in, const int* in_sizes, int n_in,
                              void* d_out, int out_size, void* d_ws, size_t ws_size,
                              hipStream_t stream) {
  (void)in_sizes; (void)n_in; (void)out_size; (void)ws_size;
  const float* vis = (const float*)d_in[0];
  const float* txt = (const float*)d_in[1];
  const float* W1i = (const float*)d_in[2];
  const float* b1i = (const float*)d_in[3];
  const float* W2i = (const float*)d_in[4];
  const float* b2i = (const float*)d_in[5];
  const float* W1g = (const float*)d_in[6];
  const float* b1g = (const float*)d_in[7];
  const float* W2g = (const float*)d_in[8];
  const float* b2g = (const float*)d_in[9];
  const int* organ = (const int*)d_in[10];

  float* out_imm = (float*)d_out;
  float* out_gene = out_imm + B_N;
  float* out_vis = out_gene + (size_t)B_N * GG;
  float* out_txt = out_vis + (size_t)B_N * DV;

  int* hdr = (int*)d_ws;
  int* perm = hdr + 128;

  const size_t OFF_ABUF = 32768;
  const size_t OFF_H1 = OFF_ABUF + (size_t)PERM_N * DD * 2;
  const size_t OFF_H2 = OFF_H1 + (size_t)PERM_N * HH * 2;
  const size_t OFF_W1I = OFF_H2 + (size_t)PERM_N * HH * 2;
  const size_t OFF_W1G = OFF_W1I + (size_t)EE * HH * DD * 2;
  const size_t OFF_W2G = OFF_W1G + (size_t)EE * HH * DD * 2;
  unsigned short* Abuf = (unsigned short*)((char*)d_ws + OFF_ABUF);
  unsigned short* H1 = (unsigned short*)((char*)d_ws + OFF_H1);
  unsigned short* H2 = (unsigned short*)((char*)d_ws + OFF_H2);
  unsigned short* W1i_t = (unsigned short*)((char*)d_ws + OFF_W1I);
  unsigned short* W1g_t = (unsigned short*)((char*)d_ws + OFF_W1G);
  unsigned short* W2g_t = (unsigned short*)((char*)d_ws + OFF_W2G);

  routing<<<1, 1024, 0, stream>>>(organ, hdr, perm);
  k_prep<<<G_CVT1 * 2 + G_AB, 256, 0, stream>>>(W1i, W1g, W1i_t, W1g_t, vis,
                                                txt, hdr, perm, Abuf);
  k_main1<<<G_G1 + G_CVT2 + G_COPY, 256, 0, stream>>>(
      Abuf, W1i_t, W1g_t, b1i, b1g, hdr, H1, H2, W2g, W2g_t,
      (const float4*)vis, (const float4*)txt, (float4*)out_vis,
      (float4*)out_txt);
  k_main2<<<G_G2 + PERM_N / 4, 256, 0, stream>>>(H2, W2g_t, b2g, hdr, perm,
                                                 out_gene, H1, W2i, b2i,
                                                 out_imm);
}

// Round 15
// 252.638 us; speedup vs baseline: 1.2118x; 1.2118x over previous
//
#include <hip/hip_runtime.h>

// MultiHeadModel routed MoE (E=8), round 15.
// = round 11 (best passing bf16-weight structure) with ONE change:
//   copy_vt moved k_main1 -> k_prep. k_main1 was BW-saturated (365 MB @
//   ~3.1 TB/s effective); k_prep streams at ~6+ TB/s. Net predicted ~-10 us.
// Everything else verbatim r11 (GEMM core schedule proven r7/r8/r9/r11).
//   routing -> k_prep{cvtW1i ∥ cvtW1g ∥ a_build ∥ copy_vt}
//           -> k_main1{gemm_l1 both heads ∥ cvtW2g}
//           -> k_main2{gemm_l2 ∥ immune}

#define B_N 4096
#define DV  1024
#define DD  2048
#define HH  1024
#define GG  4096
#define EE  8
#define BM  128
#define MAXRB 40
#define PERM_N (MAXRB * BM)

typedef __bf16 bf16x8 __attribute__((ext_vector_type(8)));
typedef float f32x4 __attribute__((ext_vector_type(4)));
typedef unsigned short u16x8v __attribute__((ext_vector_type(8)));

#define H_CNT 0
#define H_FIL 8
#define H_OFF 16
#define H_NRB 24
#define H_BLK 32

static __device__ __forceinline__ unsigned short f2bf(float f) {
  return __builtin_bit_cast(unsigned short, (__bf16)f);
}
static __device__ __forceinline__ float bf2f(unsigned short s) {
  return __builtin_bit_cast(float, (unsigned)s << 16);
}
static __device__ __forceinline__ void gload16(const void* g, void* l) {
  __builtin_amdgcn_global_load_lds(
      (const __attribute__((address_space(1))) unsigned int*)g,
      (__attribute__((address_space(3))) unsigned int*)l, 16, 0, 0);
}

// ---------------- routing: one block, 1024 threads ---------------------------
__global__ __launch_bounds__(1024) void routing(const int* __restrict__ organ,
                                                int* __restrict__ hdr,
                                                int* __restrict__ perm) {
  __shared__ int cnt[EE], fil[EE], off[EE];
  const int tid = threadIdx.x;
  if (tid < EE) { cnt[tid] = 0; fil[tid] = 0; }
  __syncthreads();
#pragma unroll
  for (int i = 0; i < 4; ++i) atomicAdd(&cnt[organ[tid + (i << 10)]], 1);
#pragma unroll
  for (int i = 0; i < 5; ++i) perm[tid + (i << 10)] = -1;
  __syncthreads();
  if (tid == 0) {
    int acc = 0;
    for (int e = 0; e < EE; ++e) {
      off[e] = acc;
      hdr[H_OFF + e] = acc;
      hdr[H_CNT + e] = cnt[e];
      int nb = (cnt[e] + BM - 1) >> 7;
      int rb0 = acc >> 7;
      for (int i = 0; i < nb; ++i) hdr[H_BLK + rb0 + i] = e;
      acc += nb << 7;
    }
    hdr[H_NRB] = acc >> 7;
  }
  __syncthreads();
#pragma unroll
  for (int i = 0; i < 4; ++i) {
    int b = tid + (i << 10);
    int e = organ[b];
    int slot = off[e] + atomicAdd(&fil[e], 1);
    perm[slot] = b;
  }
}

// ---------------- weight convert+transpose: fp32 [e][K][N] -> bf16 [e][N][K] -
static __device__ __forceinline__ void wcvt_body(
    const float* __restrict__ in, unsigned short* __restrict__ out,
    int K, int N, int bx, unsigned short* ls) {  // ls: 64*72 shorts
  const int nn = N >> 6, nk = K >> 6;
  const int e = bx / (nk * nn);
  int rem = bx - e * nk * nn;
  const int K0 = (rem / nn) << 6, N0 = (rem % nn) << 6;
  const size_t ein = (size_t)e * K * N;
  const int tid = threadIdx.x;
  const int kr = tid >> 4, n0 = (tid & 15) << 2;
#pragma unroll
  for (int p = 0; p < 4; ++p) {
    int k = (p << 4) + kr;
    float4 f = *(const float4*)&in[ein + (size_t)(K0 + k) * N + N0 + n0];
    ls[(n0 + 0) * 72 + k] = f2bf(f.x);
    ls[(n0 + 1) * 72 + k] = f2bf(f.y);
    ls[(n0 + 2) * 72 + k] = f2bf(f.z);
    ls[(n0 + 3) * 72 + k] = f2bf(f.w);
  }
  __syncthreads();
  const int n = tid >> 2, kc = (tid & 3) << 4;
  u16x8v a = *(const u16x8v*)&ls[n * 72 + kc];
  u16x8v b = *(const u16x8v*)&ls[n * 72 + kc + 8];
  size_t o = (size_t)e * N * K + (size_t)(N0 + n) * K + K0 + kc;
  *(u16x8v*)&out[o] = a;
  *(u16x8v*)&out[o + 8] = b;
}

// ---------------- a_build: 4 rows per block ----------------------------------
static __device__ __forceinline__ void abuild_body(
    int bx, const float* __restrict__ vis, const float* __restrict__ txt,
    const int* __restrict__ hdr, const int* __restrict__ perm,
    unsigned short* __restrict__ Abuf) {
  const int nr = hdr[H_NRB] << 7;
  const int tid = threadIdx.x;
  const int c = tid << 3;
  const float* srcbase = (c < DV) ? vis : txt;
  const int cc = (c < DV) ? c : c - DV;
#pragma unroll
  for (int p = 0; p < 4; ++p) {
    int r = (bx << 2) + p;
    if (r >= nr) return;
    int smp = perm[r];
    u16x8v v;
    if (smp >= 0) {
      const float* src = srcbase + (size_t)smp * 1024 + cc;
      float4 a = *(const float4*)src, b = *(const float4*)(src + 4);
      v[0] = f2bf(a.x); v[1] = f2bf(a.y); v[2] = f2bf(a.z); v[3] = f2bf(a.w);
      v[4] = f2bf(b.x); v[5] = f2bf(b.y); v[6] = f2bf(b.z); v[7] = f2bf(b.w);
    } else {
#pragma unroll
      for (int i = 0; i < 8; ++i) v[i] = 0;
    }
    *(u16x8v*)&Abuf[(size_t)r * DD + c] = v;
  }
}

static __device__ __forceinline__ void copy_body(
    int bx, const float4* __restrict__ v, const float4* __restrict__ t,
    float4* __restrict__ ov, float4* __restrict__ ot) {
  const int n4 = B_N * DV / 4;
  for (int i = bx * 256 + (int)threadIdx.x; i < n4; i += 1024 * 256) {
    ov[i] = v[i];
    ot[i] = t[i];
  }
}

// ---------------- GEMM core (r11 verbatim): A gload_lds 3-buf, B reg-staged --
// LDS shorts: A bufs 3 x 4096 @0; B bufs 2 x 4096 @12288 (40 KiB total).
template <int KDIM>
static __device__ __forceinline__ void gemm_bb(
    const unsigned short* __restrict__ Aseg,  // [128][KDIM] bf16 row-major
    const unsigned short* __restrict__ Bseg,  // [128][KDIM] bf16 n-major
    unsigned short* smem, f32x4 (&acc)[4][4]) {
  const int tid = threadIdx.x;
  const int lane = tid & 63;
  const int wr = ((tid >> 6) >> 1) << 6, wc = ((tid >> 6) & 1) << 6;
  const int lr = lane & 15;
  const int arow = tid >> 2;
  const int kq = (((tid & 3) ^ ((arow >> 1) & 3)) << 3);
  const int wbase = (tid & 192) << 3;
  const int bn = tid & 127;              // B row (n)
  const int bc0 = (tid >> 7) << 1;       // global chunk base: 0 or 2
  const int bs = (bn >> 1) & 3;
  const int bslot0 = ((bc0 ^ bs) << 3);
  const int bslot1 = (((bc0 + 1) ^ bs) << 3);
  constexpr int NT = KDIM / 32;

  u16x8v bvE[2], bvO[2];

  auto issueA = [&](int ab, int k0) {
    unsigned short* d = smem + ab * 4096 + wbase;
    gload16(Aseg + (size_t)arow * KDIM + k0 + kq, d);
    gload16(Aseg + (size_t)(64 + arow) * KDIM + k0 + kq, d + 2048);
  };
  auto issueB = [&](u16x8v (&bv)[2], int k0) {
    const unsigned short* p = Bseg + (size_t)bn * KDIM + k0 + (bc0 << 3);
    bv[0] = *(const u16x8v*)p;
    bv[1] = *(const u16x8v*)(p + 8);
  };
  auto writeB = [&](int bb, u16x8v (&bv)[2]) {
    unsigned short* row = smem + 12288 + bb * 4096 + (bn << 5);
    *(u16x8v*)(row + bslot0) = bv[0];
    *(u16x8v*)(row + bslot1) = bv[1];
  };
  auto compute = [&](int ab, int bb) {
    bf16x8 af[4], bfr[4];
#pragma unroll
    for (int m = 0; m < 4; ++m) {
      const int r = wr + m * 16 + lr;
      const int cs = ((lane >> 4) ^ ((r >> 1) & 3)) << 3;
      af[m] = *(const bf16x8*)&smem[ab * 4096 + r * 32 + cs];
    }
#pragma unroll
    for (int n = 0; n < 4; ++n) {
      const int fr = wc + n * 16 + lr;
      const int cs = ((lane >> 4) ^ ((fr >> 1) & 3)) << 3;
      bfr[n] = *(const bf16x8*)&smem[12288 + bb * 4096 + fr * 32 + cs];
    }
#pragma unroll
    for (int m = 0; m < 4; ++m)
#pragma unroll
      for (int n = 0; n < 4; ++n)
        acc[m][n] = __builtin_amdgcn_mfma_f32_16x16x32_bf16(af[m], bfr[n], acc[m][n], 0, 0, 0);
  };

  issueA(0, 0);
  __builtin_amdgcn_sched_barrier(0);
  issueB(bvE, 0);
  writeB(0, bvE);
  issueA(1, 32);
  __builtin_amdgcn_sched_barrier(0);
  issueB(bvO, 32);
  asm volatile("s_waitcnt lgkmcnt(0)" ::: "memory");
  __builtin_amdgcn_s_barrier();
  __builtin_amdgcn_sched_barrier(0);

  auto phase = [&](int t, int abI, int abC, u16x8v (&bvIss)[2],
                   u16x8v (&bvWr)[2], int bbW, int bbC) {
    if (t + 2 < NT) issueA(abI, (t + 2) << 5);
    __builtin_amdgcn_sched_barrier(0);
    if (t + 2 < NT) issueB(bvIss, (t + 2) << 5);
    __builtin_amdgcn_sched_barrier(0);
    compute(abC, bbC);
    if (t + 1 < NT) writeB(bbW, bvWr);
    asm volatile("s_waitcnt lgkmcnt(0)" ::: "memory");
    __builtin_amdgcn_s_barrier();
    __builtin_amdgcn_sched_barrier(0);
  };

  int abI = 2, abC = 0;
  for (int t = 0; t < NT; t += 2) {
    phase(t, abI, abC, bvE, bvO, 1, 0);
    abI = (abI == 2) ? 0 : abI + 1;
    abC = (abC == 2) ? 0 : abC + 1;
    phase(t + 1, abI, abC, bvO, bvE, 0, 1);
    abI = (abI == 2) ? 0 : abI + 1;
    abC = (abC == 2) ? 0 : abC + 1;
  }
}

// ---------------- k_prep: cvt(W1i) ∥ cvt(W1g) ∥ a_build ∥ copy_vt ------------
#define G_CVT1 (EE * (DD >> 6) * (HH >> 6))   // 4096
#define G_AB   (PERM_N / 4)                   // 1280
#define G_COPY 1024
__global__ __launch_bounds__(256) void k_prep(
    const float* __restrict__ W1i, const float* __restrict__ W1g,
    unsigned short* __restrict__ W1i_t, unsigned short* __restrict__ W1g_t,
    const float* __restrict__ vis, const float* __restrict__ txt,
    const int* __restrict__ hdr, const int* __restrict__ perm,
    unsigned short* __restrict__ Abuf, float4* __restrict__ ov,
    float4* __restrict__ ot) {
  __shared__ __align__(16) unsigned short sm[64 * 72];
  int bx = blockIdx.x;
  if (bx < G_CVT1) { wcvt_body(W1i, W1i_t, DD, HH, bx, sm); return; }
  bx -= G_CVT1;
  if (bx < G_CVT1) { wcvt_body(W1g, W1g_t, DD, HH, bx, sm); return; }
  bx -= G_CVT1;
  if (bx < G_AB) { abuild_body(bx, vis, txt, hdr, perm, Abuf); return; }
  bx -= G_AB;
  copy_body(bx, (const float4*)vis, (const float4*)txt, ov, ot);
}

// ---------------- k_main1: gemm_l1 (both heads) ∥ cvtW2g ---------------------
#define G_G1   (MAXRB * 16)                   // 640
#define G_CVT2 (EE * (HH >> 6) * (GG >> 6))   // 8192
__global__ __launch_bounds__(256) void k_main1(
    const unsigned short* __restrict__ Abuf,
    const unsigned short* __restrict__ W1i_t, const unsigned short* __restrict__ W1g_t,
    const float* __restrict__ b1i, const float* __restrict__ b1g,
    const int* __restrict__ hdr, unsigned short* __restrict__ H1,
    unsigned short* __restrict__ H2, const float* __restrict__ W2g,
    unsigned short* __restrict__ W2g_t) {
  __shared__ __align__(16) unsigned short smem[20480];  // 40 KiB
  int bx = blockIdx.x;
  if (bx >= G_G1) { wcvt_body(W2g, W2g_t, HH, GG, bx - G_G1, smem); return; }
  const int id = (bx & 7) * (G_G1 >> 3) + (bx >> 3);  // XCD swizzle (640%8==0)
  const int rb = id % MAXRB;
  if (rb >= hdr[H_NRB]) return;
  const int sub = id / MAXRB, head = sub >> 3, cb = (sub & 7) << 7;
  const int e = hdr[H_BLK + rb];
  const unsigned short* Wt = (head ? W1g_t : W1i_t) + (size_t)e * HH * DD + (size_t)cb * DD;
  const float* bias = (head ? b1g : b1i) + e * HH;
  unsigned short* Hout = head ? H2 : H1;
  const int tid = threadIdx.x;
  const int lane = tid & 63, wave = tid >> 6;
  const int wr = (wave >> 1) << 6, wc = (wave & 1) << 6;
  const int lr = lane & 15;

  f32x4 acc[4][4];
#pragma unroll
  for (int m = 0; m < 4; ++m)
#pragma unroll
    for (int n = 0; n < 4; ++n) acc[m][n] = (f32x4){0.f, 0.f, 0.f, 0.f};

  gemm_bb<DD>(Abuf + (size_t)rb * BM * DD, Wt, smem, acc);
  __syncthreads();

  // epilogue: bias+relu -> bf16 swizzled LDS -> coalesced 16B stores
  const int r0l = wr + ((lane >> 4) << 2);
#pragma unroll
  for (int n = 0; n < 4; ++n) {
    const int col = wc + n * 16 + lr;
    const float bv = bias[cb + col];
#pragma unroll
    for (int m = 0; m < 4; ++m)
#pragma unroll
      for (int v = 0; v < 4; ++v) {
        int row = r0l + m * 16 + v;
        float x = acc[m][n][v] + bv;
        x = x > 0.f ? x : 0.f;
        smem[((row << 7) + col) ^ ((row & 7) << 3)] = f2bf(x);
      }
  }
  __syncthreads();
#pragma unroll
  for (int c = 0; c < 8; ++c) {
    int q = c * 256 + tid;
    int row = q >> 4, ch = q & 15;
    int off = ((row << 7) + (ch << 3)) ^ ((row & 7) << 3);
    u16x8v val = *(const u16x8v*)&smem[off];
    *(u16x8v*)&Hout[(size_t)(rb * BM + row) * HH + cb + (ch << 3)] = val;
  }
}

// ---------------- immune dot -------------------------------------------------
static __device__ __forceinline__ void immune_body(
    int bx, const int* __restrict__ hdr, const int* __restrict__ perm,
    const unsigned short* __restrict__ H1, const float* __restrict__ W2,
    const float* __restrict__ b2, float* __restrict__ out) {
  const int nrb = hdr[H_NRB];
  const int r = bx * 4 + (threadIdx.x >> 6);
  if (r >= nrb * BM) return;
  const int b = perm[r];
  if (b < 0) return;
  const int e = hdr[H_BLK + (r >> 7)];
  const int lane = threadIdx.x & 63;
  const unsigned short* h = H1 + (size_t)r * HH + lane * 16;
  const float* w = W2 + (size_t)e * HH + lane * 16;
  float s = 0.f;
#pragma unroll
  for (int i = 0; i < 16; ++i) s += bf2f(h[i]) * w[i];
#pragma unroll
  for (int off = 32; off >= 1; off >>= 1) s += __shfl_xor(s, off, 64);
  if (lane == 0) out[b] = s + b2[e];
}

// ---------------- k_main2: gemm_l2 ∥ immune ----------------------------------
#define G_G2 (MAXRB * 32)   // 1280
__global__ __launch_bounds__(256) void k_main2(
    const unsigned short* __restrict__ H2buf,
    const unsigned short* __restrict__ W2g_t, const float* __restrict__ b2g,
    const int* __restrict__ hdr, const int* __restrict__ perm,
    float* __restrict__ outg, const unsigned short* __restrict__ H1,
    const float* __restrict__ W2i, const float* __restrict__ b2i,
    float* __restrict__ outi) {
  __shared__ __align__(16) unsigned short smem[20480];  // 40 KiB
  int bx = blockIdx.x;
  if (bx >= G_G2) {
    immune_body(bx - G_G2, hdr, perm, H1, W2i, b2i, outi);
    return;
  }
  const int id = (bx & 7) * (G_G2 >> 3) + (bx >> 3);  // XCD swizzle (1280%8==0)
  const int rb = id % MAXRB;
  if (rb >= hdr[H_NRB]) return;
  const int cb = (id / MAXRB) << 7;
  const int e = hdr[H_BLK + rb];
  const unsigned short* Wt = W2g_t + (size_t)e * GG * HH + (size_t)cb * HH;
  const int tid = threadIdx.x;
  const int lane = tid & 63, wave = tid >> 6;
  const int wr = (wave >> 1) << 6, wc = (wave & 1) << 6;
  const int lr = lane & 15;

  f32x4 acc[4][4];
#pragma unroll
  for (int m = 0; m < 4; ++m)
#pragma unroll
    for (int n = 0; n < 4; ++n) acc[m][n] = (f32x4){0.f, 0.f, 0.f, 0.f};

  gemm_bb<HH>(H2buf + (size_t)rb * BM * HH, Wt, smem, acc);
  __syncthreads();

  // epilogue: bias -> bf16 swizzled LDS -> fp32 scatter rows via perm
  const int r0l = wr + ((lane >> 4) << 2);
#pragma unroll
  for (int n = 0; n < 4; ++n) {
    const int col = wc + n * 16 + lr;
    const float bv = b2g[e * GG + cb + col];
#pragma unroll
    for (int m = 0; m < 4; ++m)
#pragma unroll
      for (int v = 0; v < 4; ++v) {
        int row = r0l + m * 16 + v;
        smem[((row << 7) + col) ^ ((row & 7) << 3)] = f2bf(acc[m][n][v] + bv);
      }
  }
  __syncthreads();
#pragma unroll
  for (int c = 0; c < 8; ++c) {
    int q = c * 256 + tid;
    int row = q >> 4, ch = q & 15;
    int sm = perm[rb * BM + row];
    if (sm < 0) continue;
    int off = ((row << 7) + (ch << 3)) ^ ((row & 7) << 3);
    u16x8v val = *(const u16x8v*)&smem[off];
    float4 f0, f1;
    f0.x = bf2f(val[0]); f0.y = bf2f(val[1]); f0.z = bf2f(val[2]); f0.w = bf2f(val[3]);
    f1.x = bf2f(val[4]); f1.y = bf2f(val[5]); f1.z = bf2f(val[6]); f1.w = bf2f(val[7]);
    float* dst = outg + (size_t)sm * GG + cb + (ch << 3);
    *(float4*)dst = f0;
    *(float4*)(dst + 4) = f1;
  }
}

// ================= host ======================================================
extern "C" void kernel_launch(void* const* d_in, const int* in_sizes, int n_in,
                              void* d_out, int out_size, void* d_ws, size_t ws_size,
                              hipStream_t stream) {
  (void)in_sizes; (void)n_in; (void)out_size; (void)ws_size;
  const float* vis = (const float*)d_in[0];
  const float* txt = (const float*)d_in[1];
  const float* W1i = (const float*)d_in[2];
  const float* b1i = (const float*)d_in[3];
  const float* W2i = (const float*)d_in[4];
  const float* b2i = (const float*)d_in[5];
  const float* W1g = (const float*)d_in[6];
  const float* b1g = (const float*)d_in[7];
  const float* W2g = (const float*)d_in[8];
  const float* b2g = (const float*)d_in[9];
  const int* organ = (const int*)d_in[10];

  float* out_imm = (float*)d_out;
  float* out_gene = out_imm + B_N;
  float* out_vis = out_gene + (size_t)B_N * GG;
  float* out_txt = out_vis + (size_t)B_N * DV;

  int* hdr = (int*)d_ws;
  int* perm = hdr + 128;

  const size_t OFF_ABUF = 32768;
  const size_t OFF_H1 = OFF_ABUF + (size_t)PERM_N * DD * 2;
  const size_t OFF_H2 = OFF_H1 + (size_t)PERM_N * HH * 2;
  const size_t OFF_W1I = OFF_H2 + (size_t)PERM_N * HH * 2;
  const size_t OFF_W1G = OFF_W1I + (size_t)EE * HH * DD * 2;
  const size_t OFF_W2G = OFF_W1G + (size_t)EE * HH * DD * 2;
  unsigned short* Abuf = (unsigned short*)((char*)d_ws + OFF_ABUF);
  unsigned short* H1 = (unsigned short*)((char*)d_ws + OFF_H1);
  unsigned short* H2 = (unsigned short*)((char*)d_ws + OFF_H2);
  unsigned short* W1i_t = (unsigned short*)((char*)d_ws + OFF_W1I);
  unsigned short* W1g_t = (unsigned short*)((char*)d_ws + OFF_W1G);
  unsigned short* W2g_t = (unsigned short*)((char*)d_ws + OFF_W2G);

  routing<<<1, 1024, 0, stream>>>(organ, hdr, perm);
  k_prep<<<G_CVT1 * 2 + G_AB + G_COPY, 256, 0, stream>>>(
      W1i, W1g, W1i_t, W1g_t, vis, txt, hdr, perm, Abuf, (float4*)out_vis,
      (float4*)out_txt);
  k_main1<<<G_G1 + G_CVT2, 256, 0, stream>>>(Abuf, W1i_t, W1g_t, b1i, b1g, hdr,
                                             H1, H2, W2g, W2g_t);
  k_main2<<<G_G2 + PERM_N / 4, 256, 0, stream>>>(H2, W2g_t, b2g, hdr, perm,
                                                 out_gene, H1, W2i, b2i,
                                                 out_imm);
}